// Round 2
// baseline (4608.826 us; speedup 1.0000x reference)
//
#include <hip/hip_runtime.h>
#include <hip/hip_bf16.h>

// SimpleBiGRU on MI355X — R2: 1-wave workgroups, no LDS staging.
// Both "directions" are forward-in-time GRU scans (batch-flip is identity).
// 8 units = (dir) x (batch-group of 16 rows); 32 WGs (1 wave each) per unit,
// each owning 16 hidden columns x 3 gates. h broadcast via bf16 row-major
// global buffer (agent-scope atomics, LLC); fp32 carry in registers.

#define TT 512
#define FF 256
#define HH 512
#define G3 1536
#define NSLICE 32
#define NWG 256
#define NTHR 64

typedef __attribute__((ext_vector_type(8))) short short8;   // 8 x bf16
typedef __attribute__((ext_vector_type(4))) float f32x4;

__device__ __forceinline__ unsigned short f2bf(float f) {
  union { float f; unsigned u; } x; x.f = f;
  return (unsigned short)((x.u + 0x7fffu + ((x.u >> 16) & 1u)) >> 16);  // RNE
}

__device__ __forceinline__ unsigned pk2(float a, float b) {
  union { __hip_bfloat162 h; unsigned u; } x;
  x.h = __float22bfloat162_rn(make_float2(a, b));
  return x.u;  // low 16 = a, high 16 = b
}

__device__ __forceinline__ float sigm(float x) {
  return __builtin_amdgcn_rcpf(1.f + __expf(-x));
}

#define MFMA(a, b, c) __builtin_amdgcn_mfma_f32_16x16x32_bf16((a), (b), (c), 0, 0, 0)

__global__ __launch_bounds__(NTHR, 1) void gru_fused(
    const float* __restrict__ data,
    const float* __restrict__ Wi_f, const float* __restrict__ bi_f,
    const float* __restrict__ Wh_f, const float* __restrict__ bhn_f,
    const float* __restrict__ Wi_b, const float* __restrict__ bi_b,
    const float* __restrict__ Wh_b, const float* __restrict__ bhn_b,
    float* __restrict__ out,
    unsigned long long* __restrict__ hbuf,  // [unit][buf][row16][col512] bf16 as u64 chunks
    int* __restrict__ flags)                // [unit][TT]
{
  const int wg   = blockIdx.x;
  const int unit = wg & 7;      // same-XCD heuristic for a unit's 32 WGs
  const int s    = wg >> 3;     // column slice 0..31
  const int dir  = unit >> 2;
  const int bg   = unit & 3;
  const int lane = threadIdx.x; // 0..63
  const int l15  = lane & 15;
  const int lg   = lane >> 4;

  const float* Wi  = dir ? Wi_b  : Wi_f;
  const float* Wh  = dir ? Wh_b  : Wh_f;
  const float* bi  = dir ? bi_b  : bi_f;
  const float* bhn = dir ? bhn_b : bhn_f;

  const int colT = s * 16 + l15;  // this lane's output column (B n-index = l15)

  // ---- one-time: weight B-fragments into registers ----
  // k-slot mapping k = ks*32 + lg*8 + j, identical for A and B (layout-safe).
  short8 whf[3][16];
#pragma unroll
  for (int g = 0; g < 3; ++g)
#pragma unroll
    for (int ks = 0; ks < 16; ++ks) {
      short8 v;
#pragma unroll
      for (int j = 0; j < 8; ++j)
        v[j] = (short)f2bf(Wh[(size_t)(ks * 32 + lg * 8 + j) * G3 + g * HH + colT]);
      whf[g][ks] = v;
    }
  short8 wif[3][8];
#pragma unroll
  for (int g = 0; g < 3; ++g)
#pragma unroll
    for (int ks = 0; ks < 8; ++ks) {
      short8 v;
#pragma unroll
      for (int j = 0; j < 8; ++j)
        v[j] = (short)f2bf(Wi[(size_t)(ks * 32 + lg * 8 + j) * G3 + g * HH + colT]);
      wif[g][ks] = v;
    }
  const float biR = bi[colT], biZ = bi[HH + colT], biN = bi[2 * HH + colT];
  const float bhnc = bhn[colT];

  int* myflags = flags + unit * TT;
  const float* xbase = data + (size_t)(bg * 16 + l15) * TT * FF;  // A m-index = l15

  __shared__ __align__(16) unsigned short tile[16][16];  // 512B transpose tile

  float hp[4] = {0.f, 0.f, 0.f, 0.f};  // fp32 carry: rows lg*4+j, col colT

  for (int t = 0; t < TT; ++t) {
    const int ib = t & 1;

    // ---- xg phase (h-independent, overlaps other WGs' release latency) ----
    f32x4 accR = {0.f, 0.f, 0.f, 0.f};
    f32x4 accZ = {0.f, 0.f, 0.f, 0.f};
    f32x4 xN   = {0.f, 0.f, 0.f, 0.f};
    {
      const float* xr = xbase + (size_t)t * FF;
#pragma unroll
      for (int ks = 0; ks < 8; ++ks) {
        float4 x0 = *(const float4*)(xr + ks * 32 + lg * 8);
        float4 x1 = *(const float4*)(xr + ks * 32 + lg * 8 + 4);
        union { short8 s; unsigned u[4]; } a;
        a.u[0] = pk2(x0.x, x0.y); a.u[1] = pk2(x0.z, x0.w);
        a.u[2] = pk2(x1.x, x1.y); a.u[3] = pk2(x1.z, x1.w);
        accR = MFMA(a.s, wif[0][ks], accR);
        accZ = MFMA(a.s, wif[1][ks], accZ);
        xN   = MFMA(a.s, wif[2][ks], xN);
      }
    }

    // ---- wait for h(t-1) ----
    if (t > 0) {
      while (__hip_atomic_load(&myflags[t - 1], __ATOMIC_RELAXED, __HIP_MEMORY_SCOPE_AGENT) < NSLICE)
        __builtin_amdgcn_s_sleep(1);
      __builtin_amdgcn_fence(__ATOMIC_ACQUIRE, "agent");
    }

    // ---- A-fragments direct from global (32 independent loads: pipelined) ----
    const unsigned long long* hin = hbuf + (size_t)(unit * 2 + ib) * 2048;
    unsigned long long q[32];
#pragma unroll
    for (int ks = 0; ks < 16; ++ks) {
      const int bidx = l15 * 128 + ks * 8 + lg * 2;
      q[2 * ks]     = __hip_atomic_load(&hin[bidx],     __ATOMIC_RELAXED, __HIP_MEMORY_SCOPE_AGENT);
      q[2 * ks + 1] = __hip_atomic_load(&hin[bidx + 1], __ATOMIC_RELAXED, __HIP_MEMORY_SCOPE_AGENT);
    }

    // ---- hg MFMAs ----
    f32x4 hN = {0.f, 0.f, 0.f, 0.f};
#pragma unroll
    for (int ks = 0; ks < 16; ++ks) {
      union { short8 s; unsigned long long q[2]; } a;
      a.q[0] = q[2 * ks]; a.q[1] = q[2 * ks + 1];
      accR = MFMA(a.s, whf[0][ks], accR);
      accZ = MFMA(a.s, whf[1][ks], accZ);
      hN   = MFMA(a.s, whf[2][ks], hN);
    }

    // ---- gates (lane-local: C/D row = lg*4+j, col = l15 for all three accs) ----
    float hv[4];
#pragma unroll
    for (int j = 0; j < 4; ++j) {
      float r = sigm(accR[j] + biR);
      float z = sigm(accZ[j] + biZ);
      float e = __expf(2.f * (xN[j] + biN + r * (hN[j] + bhnc)));
      float n = 1.f - 2.f * __builtin_amdgcn_rcpf(e + 1.f);  // tanh
      hv[j] = (1.f - z) * n + z * hp[j];
      hp[j] = hv[j];
    }

    // ---- publish: in-wave 16x16 transpose via LDS, one u64 store per lane ----
#pragma unroll
    for (int j = 0; j < 4; ++j) tile[lg * 4 + j][l15] = f2bf(hv[j]);
    // read transposed: row = l15? no — row = lane&15, 4-col chunk = lane>>4
    unsigned long long pv = *(const unsigned long long*)&tile[l15][lg * 4];
    unsigned long long* hout = hbuf + (size_t)(unit * 2 + (ib ^ 1)) * 2048;
    __hip_atomic_store(&hout[l15 * 128 + s * 4 + lg], pv,
                       __ATOMIC_RELAXED, __HIP_MEMORY_SCOPE_AGENT);
    asm volatile("s_waitcnt vmcnt(0)" ::: "memory");  // drain wave's stores
    if (lane == 0)
      __hip_atomic_fetch_add(&myflags[t], 1, __ATOMIC_RELAXED, __HIP_MEMORY_SCOPE_AGENT);

    // ---- out stores after release (off the inter-WG critical path) ----
#pragma unroll
    for (int j = 0; j < 4; ++j)
      out[((size_t)(bg * 16 + lg * 4 + j) * TT + t) * 1024 + (size_t)dir * HH + colT] = hv[j];
  }
}

extern "C" void kernel_launch(void* const* d_in, const int* in_sizes, int n_in,
                              void* d_out, int out_size, void* d_ws, size_t ws_size,
                              hipStream_t stream) {
  const float* data  = (const float*)d_in[0];
  const float* Wi_f  = (const float*)d_in[1];
  const float* bi_f  = (const float*)d_in[2];
  const float* Wh_f  = (const float*)d_in[3];
  const float* bhn_f = (const float*)d_in[4];
  const float* Wi_b  = (const float*)d_in[5];
  const float* bi_b  = (const float*)d_in[6];
  const float* Wh_b  = (const float*)d_in[7];
  const float* bhn_b = (const float*)d_in[8];
  float* out = (float*)d_out;

  // ws: [0, 256KB) bf16 h double buffers; [256KB, +16KB) flags
  unsigned long long* hbuf = (unsigned long long*)d_ws;
  int* flags = (int*)((char*)d_ws + 262144);
  hipMemsetAsync(d_ws, 0, 262144 + 16384, stream);  // h0 = 0, flags = 0 (every call)

  gru_fused<<<NWG, NTHR, 0, stream>>>(data, Wi_f, bi_f, Wh_f, bhn_f,
                                      Wi_b, bi_b, Wh_b, bhn_b, out, hbuf, flags);
}

// Round 3
// 3731.511 us; speedup vs baseline: 1.2351x; 1.2351x over previous
//
#include <hip/hip_runtime.h>
#include <hip/hip_bf16.h>

// SimpleBiGRU on MI355X — R3: spin-poll, per-producer flags, swapped MFMA
// operands (no LDS at all).
// Both "directions" are forward-in-time GRU scans (batch-flip is identity).
// 8 units = (dir) x (batch-group of 16 rows); 32 WGs (1 wave each) per unit,
// each owning 16 hidden columns x 3 gates.
//
// MFMA convention (swapped): acc = MFMA(W_frag, act_frag, acc).
//   A-operand = weights: lane&15 = output column (within slice), k-slot
//   formula k = ks*32 + lg*8 + j (identical for both operands => layout-safe).
//   B-operand = activations: lane&15 = batch row, same k-slot formula.
//   D: row = 4*lg + reg = output column offset, col = l15 = batch row.
// => each lane holds 4 ADJACENT h-columns of one batch row: packed u64
//    publish, float4 out store, no transpose.

#define TT 512
#define FF 256
#define HH 512
#define G3 1536
#define NSLICE 32
#define NWG 256
#define NTHR 64

typedef __attribute__((ext_vector_type(8))) short short8;   // 8 x bf16
typedef __attribute__((ext_vector_type(4))) float f32x4;

__device__ __forceinline__ unsigned short f2bf(float f) {
  union { float f; unsigned u; } x; x.f = f;
  return (unsigned short)((x.u + 0x7fffu + ((x.u >> 16) & 1u)) >> 16);  // RNE
}

__device__ __forceinline__ unsigned pk2(float a, float b) {
  union { __hip_bfloat162 h; unsigned u; } x;
  x.h = __float22bfloat162_rn(make_float2(a, b));
  return x.u;  // low 16 = a, high 16 = b
}

__device__ __forceinline__ float sigm(float x) {
  return __builtin_amdgcn_rcpf(1.f + __expf(-x));
}

#define MFMA(a, b, c) __builtin_amdgcn_mfma_f32_16x16x32_bf16((a), (b), (c), 0, 0, 0)

__global__ __launch_bounds__(NTHR, 1) void gru_fused(
    const float* __restrict__ data,
    const float* __restrict__ Wi_f, const float* __restrict__ bi_f,
    const float* __restrict__ Wh_f, const float* __restrict__ bhn_f,
    const float* __restrict__ Wi_b, const float* __restrict__ bi_b,
    const float* __restrict__ Wh_b, const float* __restrict__ bhn_b,
    float* __restrict__ out,
    unsigned long long* __restrict__ hbuf,  // [unit][buf][row16][col512] bf16 as u64
    int* __restrict__ flags)                // [unit][producer 32]
{
  const int wg   = blockIdx.x;
  const int unit = wg & 7;
  const int s    = wg >> 3;     // column slice 0..31
  const int dir  = unit >> 2;
  const int bg   = unit & 3;
  const int lane = threadIdx.x; // 0..63
  const int l15  = lane & 15;
  const int lg   = lane >> 4;

  const float* Wi  = dir ? Wi_b  : Wi_f;
  const float* Wh  = dir ? Wh_b  : Wh_f;
  const float* bi  = dir ? bi_b  : bi_f;
  const float* bhn = dir ? bhn_b : bhn_f;

  const int colT = s * 16 + l15;        // weight-fragment column (lane&15 = m)
  const int colBase = s * 16 + lg * 4;  // this lane's 4 output columns

  // ---- one-time: weight A-fragments into registers ----
  short8 whf[3][16];
#pragma unroll
  for (int g = 0; g < 3; ++g)
#pragma unroll
    for (int ks = 0; ks < 16; ++ks) {
      short8 v;
#pragma unroll
      for (int j = 0; j < 8; ++j)
        v[j] = (short)f2bf(Wh[(size_t)(ks * 32 + lg * 8 + j) * G3 + g * HH + colT]);
      whf[g][ks] = v;
    }
  short8 wif[3][8];
#pragma unroll
  for (int g = 0; g < 3; ++g)
#pragma unroll
    for (int ks = 0; ks < 8; ++ks) {
      short8 v;
#pragma unroll
      for (int j = 0; j < 8; ++j)
        v[j] = (short)f2bf(Wi[(size_t)(ks * 32 + lg * 8 + j) * G3 + g * HH + colT]);
      wif[g][ks] = v;
    }
  // per-output-column biases (lane's 4 columns)
  float biR[4], biZ[4], biN[4], bhc[4];
#pragma unroll
  for (int j = 0; j < 4; ++j) {
    biR[j] = bi[colBase + j];
    biZ[j] = bi[HH + colBase + j];
    biN[j] = bi[2 * HH + colBase + j];
    bhc[j] = bhn[colBase + j];
  }

  int* myflags = flags + unit * 32;
  const float* xbase = data + (size_t)(bg * 16 + l15) * TT * FF;  // B m... batch = l15

  float hp[4] = {0.f, 0.f, 0.f, 0.f};  // fp32 carry: batch l15, cols colBase+j

  for (int t = 0; t < TT; ++t) {
    const int ib = t & 1;

    // ---- xg phase (h-independent, before the wait) ----
    f32x4 accR = {0.f, 0.f, 0.f, 0.f};
    f32x4 accZ = {0.f, 0.f, 0.f, 0.f};
    f32x4 xN   = {0.f, 0.f, 0.f, 0.f};
    {
      const float* xr = xbase + (size_t)t * FF;
#pragma unroll
      for (int ks = 0; ks < 8; ++ks) {
        float4 x0 = *(const float4*)(xr + ks * 32 + lg * 8);
        float4 x1 = *(const float4*)(xr + ks * 32 + lg * 8 + 4);
        union { short8 s; unsigned u[4]; } a;
        a.u[0] = pk2(x0.x, x0.y); a.u[1] = pk2(x0.z, x0.w);
        a.u[2] = pk2(x1.x, x1.y); a.u[3] = pk2(x1.z, x1.w);
        accR = MFMA(wif[0][ks], a.s, accR);
        accZ = MFMA(wif[1][ks], a.s, accZ);
        xN   = MFMA(wif[2][ks], a.s, xN);
      }
    }

    // ---- busy-spin wait: all 32 producer flags >= t (lane = producer id) ----
    if (t > 0) {
      const int fidx = lane & 31;
      while (true) {
        int fl = __hip_atomic_load(&myflags[fidx], __ATOMIC_RELAXED, __HIP_MEMORY_SCOPE_AGENT);
        if (__all(fl >= t)) break;
      }
      asm volatile("" ::: "memory");  // compiler barrier: keep data loads below
    }

    // ---- h(t-1) B-fragments direct from LLC (32 independent loads) ----
    const unsigned long long* hin = hbuf + (size_t)(unit * 2 + ib) * 2048;
    unsigned long long q[32];
#pragma unroll
    for (int ks = 0; ks < 16; ++ks) {
      const int bidx = l15 * 128 + ks * 8 + lg * 2;
      q[2 * ks]     = __hip_atomic_load(&hin[bidx],     __ATOMIC_RELAXED, __HIP_MEMORY_SCOPE_AGENT);
      q[2 * ks + 1] = __hip_atomic_load(&hin[bidx + 1], __ATOMIC_RELAXED, __HIP_MEMORY_SCOPE_AGENT);
    }

    // ---- hg MFMAs ----
    f32x4 hN = {0.f, 0.f, 0.f, 0.f};
#pragma unroll
    for (int ks = 0; ks < 16; ++ks) {
      union { short8 s; unsigned long long q[2]; } a;
      a.q[0] = q[2 * ks]; a.q[1] = q[2 * ks + 1];
      accR = MFMA(whf[0][ks], a.s, accR);
      accZ = MFMA(whf[1][ks], a.s, accZ);
      hN   = MFMA(whf[2][ks], a.s, hN);
    }

    // ---- gates: lane holds (batch=l15, col=colBase+j) ----
    float hv[4];
#pragma unroll
    for (int j = 0; j < 4; ++j) {
      float r = sigm(accR[j] + biR[j]);
      float z = sigm(accZ[j] + biZ[j]);
      float e = __expf(2.f * (xN[j] + biN[j] + r * (hN[j] + bhc[j])));
      float n = 1.f - 2.f * __builtin_amdgcn_rcpf(e + 1.f);  // tanh
      hv[j] = (1.f - z) * n + z * hp[j];
      hp[j] = hv[j];
    }

    // ---- publish: one packed u64 store (4 adjacent bf16 cols), then flag ----
    unsigned long long pv = (unsigned long long)pk2(hv[0], hv[1])
                          | ((unsigned long long)pk2(hv[2], hv[3]) << 32);
    unsigned long long* hout = hbuf + (size_t)(unit * 2 + (ib ^ 1)) * 2048;
    __hip_atomic_store(&hout[l15 * 128 + s * 4 + lg], pv,
                       __ATOMIC_RELAXED, __HIP_MEMORY_SCOPE_AGENT);
    asm volatile("s_waitcnt vmcnt(0)" ::: "memory");  // drain wave's h-store
    if (lane == 0)
      __hip_atomic_store(&myflags[s], t + 1, __ATOMIC_RELAXED, __HIP_MEMORY_SCOPE_AGENT);

    // ---- out store (off critical path): one float4 per lane ----
    *(float4*)(out + ((size_t)(bg * 16 + l15) * TT + t) * 1024 + (size_t)dir * HH + colBase)
        = make_float4(hv[0], hv[1], hv[2], hv[3]);
  }
}

extern "C" void kernel_launch(void* const* d_in, const int* in_sizes, int n_in,
                              void* d_out, int out_size, void* d_ws, size_t ws_size,
                              hipStream_t stream) {
  const float* data  = (const float*)d_in[0];
  const float* Wi_f  = (const float*)d_in[1];
  const float* bi_f  = (const float*)d_in[2];
  const float* Wh_f  = (const float*)d_in[3];
  const float* bhn_f = (const float*)d_in[4];
  const float* Wi_b  = (const float*)d_in[5];
  const float* bi_b  = (const float*)d_in[6];
  const float* Wh_b  = (const float*)d_in[7];
  const float* bhn_b = (const float*)d_in[8];
  float* out = (float*)d_out;

  // ws: [0, 256KB) bf16 h double buffers; [256KB, +4KB) flags
  unsigned long long* hbuf = (unsigned long long*)d_ws;
  int* flags = (int*)((char*)d_ws + 262144);
  hipMemsetAsync(d_ws, 0, 262144 + 4096, stream);  // h0 = 0, flags = 0 (every call)

  gru_fused<<<NWG, NTHR, 0, stream>>>(data, Wi_f, bi_f, Wh_f, bhn_f,
                                      Wi_b, bi_b, Wh_b, bhn_b, out, hbuf, flags);
}